// Round 1
// baseline (391.101 us; speedup 1.0000x reference)
//
#include <hip/hip_runtime.h>
#include <hip/hip_cooperative_groups.h>
#include <cstdint>
#include <cstddef>

#define N_NODES 8192
#define F_OUT   64
#define DINT    32
#define ALPHA   0.2f

namespace cg = cooperative_groups;

__device__ __forceinline__ unsigned long long pack_vi(float v, int idx) {
    unsigned int b = __float_as_uint(v);
    b = (b & 0x80000000u) ? ~b : (b | 0x80000000u);   // sortable uint
    return ((unsigned long long)b << 32) | (unsigned int)idx;
}

// ---------------------------------------------------------------------------
// K1: h = x @ W, fused s,t projections + packed sortable keys su/tu.
// One wave per row.
// ---------------------------------------------------------------------------
__global__ __launch_bounds__(64) void k_h_st(
    const float* __restrict__ x, const float* __restrict__ ie,
    const float* __restrict__ W, const float* __restrict__ a,
    float* __restrict__ h, float* __restrict__ s, float* __restrict__ t,
    unsigned long long* __restrict__ su, unsigned long long* __restrict__ tu)
{
    const int i = blockIdx.x;
    const int f = threadIdx.x;              // 0..63
    const float* xr = x + (size_t)i * 64;

    float acc = 0.f;
    #pragma unroll 16
    for (int k = 0; k < 64; ++k)
        acc = fmaf(xr[k], W[k * 64 + f], acc);

    h[(size_t)i * 64 + f] = acc;

    float ps = acc * a[f];
    float pt = acc * a[64 + f];
    if (f < DINT) {
        float e = ie[(size_t)i * DINT + f];
        ps = fmaf(e, a[128 + f], ps);
        pt = fmaf(e, a[160 + f], pt);
    }
    #pragma unroll
    for (int m = 1; m < 64; m <<= 1) {
        ps += __shfl_xor(ps, m, 64);
        pt += __shfl_xor(pt, m, 64);
    }
    if (f == 0) {
        s[i] = ps; t[i] = pt;
        su[i] = pack_vi(ps, i);
        tu[i] = pack_vi(pt, i);
    }
}

// ---------------------------------------------------------------------------
// K2: ranks/counts. 8 keys per wave, 4 waves/block => 32 keys/block.
// Keys pre-packed (K1). LDS staging uses stride-256 element mapping:
// ds_write addr/4 = 2*tid (+512e) -> 4 accesses/bank = conflict-minimal,
// and the global loads are unit-stride coalesced.
//  which==0 (keys=s): rank_s -> scatter se1/se2; pos[i]=#{j: t_j < -s_i};
//                     wave u64-max of s gives smax for free.
//  which==1 (keys=t): inv_t[rank]=j, t_sorted[rank]=t_j, q[rank]=#{i: s_i<-t_j}.
// ---------------------------------------------------------------------------
__global__ __launch_bounds__(256) void k_ranks(
    const float* __restrict__ s, const float* __restrict__ t,
    const unsigned long long* __restrict__ su,
    const unsigned long long* __restrict__ tu,
    float* __restrict__ smax,
    int* __restrict__ pos, int* __restrict__ inv_t,
    float* __restrict__ t_sorted, int* __restrict__ q_sorted,
    float* __restrict__ se1, float* __restrict__ se2)
{
    __shared__ __align__(16) unsigned long long u_sh[2048];
    __shared__ __align__(16) float f_sh[2048];
    const int tid  = threadIdx.x;
    const int wave = __builtin_amdgcn_readfirstlane(tid) >> 6;
    const int lane = tid & 63;
    const int which = blockIdx.y;
    const int key0 = blockIdx.x * 32 + wave * 8;

    const float* __restrict__ karr = (which == 0) ? s : t;
    const unsigned long long* __restrict__ kuarr = (which == 0) ? su : tu;
    const float* __restrict__ oarr = (which == 0) ? t : s;

    float kf[8], nk[8];
    unsigned long long ku[8];
    #pragma unroll
    for (int l = 0; l < 8; ++l) {
        kf[l] = karr[key0 + l];
        ku[l] = kuarr[key0 + l];
        nk[l] = -kf[l];
    }

    int c1[8] = {0,0,0,0,0,0,0,0}, c2[8] = {0,0,0,0,0,0,0,0};
    unsigned long long mx = 0ull;

    for (int c = 0; c < 4; ++c) {
        const int base = c * 2048;
        #pragma unroll
        for (int e = 0; e < 8; ++e) {
            u_sh[tid + e * 256] = kuarr[base + tid + e * 256];
            f_sh[tid + e * 256] = oarr[base + tid + e * 256];
        }
        __syncthreads();

        for (int k = lane * 4; k < 2048; k += 256) {
            const ulonglong2 p0 = *reinterpret_cast<const ulonglong2*>(&u_sh[k]);
            const ulonglong2 p1 = *reinterpret_cast<const ulonglong2*>(&u_sh[k + 2]);
            const float4 fv = *reinterpret_cast<const float4*>(&f_sh[k]);
            if (which == 0) {
                unsigned long long m01 = p0.x > p0.y ? p0.x : p0.y;
                unsigned long long m23 = p1.x > p1.y ? p1.x : p1.y;
                unsigned long long m03 = m01 > m23 ? m01 : m23;
                mx = mx > m03 ? mx : m03;
            }
            #pragma unroll
            for (int l = 0; l < 8; ++l) {
                c1[l] += (int)(p0.x < ku[l]) + (int)(p0.y < ku[l])
                       + (int)(p1.x < ku[l]) + (int)(p1.y < ku[l]);
                c2[l] += (int)(fv.x < nk[l]) + (int)(fv.y < nk[l])
                       + (int)(fv.z < nk[l]) + (int)(fv.w < nk[l]);
            }
        }
        __syncthreads();
    }

    int pk[8];
    #pragma unroll
    for (int l = 0; l < 8; ++l) pk[l] = c1[l] * 16384 + c2[l];
    #pragma unroll
    for (int m = 1; m < 64; m <<= 1) {
        #pragma unroll
        for (int l = 0; l < 8; ++l) pk[l] += __shfl_xor(pk[l], m, 64);
    }

    if (which == 0) {
        #pragma unroll
        for (int m = 1; m < 64; m <<= 1) {
            unsigned long long o = __shfl_xor(mx, m, 64);
            mx = mx > o ? mx : o;
        }
        if (lane == 0) {
            unsigned int b = (unsigned int)(mx >> 32);      // sortable of max s
            b = (b & 0x80000000u) ? (b ^ 0x80000000u) : ~b; // inverse map
            const float smax_f = __uint_as_float(b);
            if (key0 == 0) smax[0] = smax_f;
            #pragma unroll
            for (int l = 0; l < 8; ++l) {
                const int idx = key0 + l;
                const int r1 = pk[l] >> 14, r2 = pk[l] & 16383;
                pos[idx] = r2;
                const float d = kf[l] - smax_f;
                se1[r1] = __expf(d);
                se2[r1] = __expf(ALPHA * d);
            }
        }
    } else if (lane == 0) {
        #pragma unroll
        for (int l = 0; l < 8; ++l) {
            const int idx = key0 + l;
            const int r1 = pk[l] >> 14, r2 = pk[l] & 16383;
            inv_t[r1] = idx;
            t_sorted[r1] = kf[l];
            q_sorted[r1] = r2;
        }
    }
}

// ---------------------------------------------------------------------------
// K3 (single block, 1024 thr): fp64 scans via wave-shfl (2 barriers), then
// per-column coefficients. SufP1/PreP2 live only in LDS. (unchanged)
// ---------------------------------------------------------------------------
__global__ __launch_bounds__(1024) void k_mid(
    const float* __restrict__ se1, const float* __restrict__ se2,
    const float* __restrict__ smax_p,
    const float* __restrict__ t_sorted, const int* __restrict__ q_sorted,
    float* __restrict__ cf1, float* __restrict__ cf2)
{
    __shared__ float suf1[8200];
    __shared__ float pre2[8200];
    __shared__ double wred[2][16];
    const int tid = threadIdx.x, wave = tid >> 6, lane = tid & 63;
    const int base = tid * 8;

    double l1[8], l2[8], s1 = 0.0, s2 = 0.0;
    #pragma unroll
    for (int k = 0; k < 8; ++k) {
        l1[k] = (double)se1[base + k]; s1 += l1[k];
        l2[k] = (double)se2[base + k]; s2 += l2[k];
    }
    double i1 = s1, i2 = s2;                 // wave inclusive scan
    #pragma unroll
    for (int off = 1; off < 64; off <<= 1) {
        double v1 = __shfl_up(i1, off, 64);
        double v2 = __shfl_up(i2, off, 64);
        if (lane >= off) { i1 += v1; i2 += v2; }
    }
    if (lane == 63) { wred[0][wave] = i1; wred[1][wave] = i2; }
    __syncthreads();
    double off1 = 0, off2 = 0, tot1 = 0, tot2 = 0;
    #pragma unroll
    for (int w = 0; w < 16; ++w) {
        const double a = wred[0][w], b = wred[1][w];
        if (w < wave) { off1 += a; off2 += b; }
        tot1 += a; tot2 += b;
    }
    double run1 = off1 + (i1 - s1);          // exclusive prefix at `base`
    double run2 = off2 + (i2 - s2);
    #pragma unroll
    for (int k = 0; k < 8; ++k) {
        suf1[base + k] = (float)(tot1 - run1); run1 += l1[k];
        pre2[base + k] = (float)run2;          run2 += l2[k];
    }
    if (tid == 1023) { suf1[8192] = 0.f; pre2[8192] = (float)tot2; }
    __syncthreads();

    const float smax = smax_p[0];
    #pragma unroll
    for (int k = 0; k < 8; ++k) {
        const int r = tid + k * 1024;
        const float tj = t_sorted[r];
        const float zc = smax + tj;
        const float c = fmaxf(zc, ALPHA * zc);     // lrelu(smax+t_j) = col max
        const float E1 = __expf(zc - c);
        const float E2 = __expf(ALPHA * zc - c);
        const int qj = q_sorted[r];
        const float D = E1 * suf1[qj] + E2 * pre2[qj];
        const float invD = 1.f / D;
        cf1[r] = E1 * invD;
        cf2[r] = E2 * invD;
    }
}

// ---------------------------------------------------------------------------
// K4 (cooperative, 64 blocks x 256 thr): fused tile-sums + final scans.
// Phase 1: each wave gathers its 32 rows of h ONCE into registers, computes
//          tile totals for both cf1- and cf2-weighted sums -> T1/T2.
// grid.sync()
// Phase 2: cross-tile offsets (4-acc unrolled), intra-block wave offsets via
//          LDS, then suffix-walk S1 / prefix-walk S2 from the cached hv[].
//  S1[r] = sum_{r'>=r} cf1*h (S1[8192]=0); S2[r] = sum_{r'<r} cf2*h
//  (S2[8192]=total).
// ---------------------------------------------------------------------------
__global__ __launch_bounds__(256) void k_scan(
    const float* __restrict__ h, const int* __restrict__ inv_t,
    const float* __restrict__ cf1, const float* __restrict__ cf2,
    float* __restrict__ T1, float* __restrict__ T2,
    float* __restrict__ S1, float* __restrict__ S2)
{
    const int tile = blockIdx.x;                                   // 0..63
    const int wave = __builtin_amdgcn_readfirstlane(threadIdx.x) >> 6;
    const int f = threadIdx.x & 63;
    const int rbase = tile * 128 + wave * 32;

    float hv[32];
    #pragma unroll
    for (int k = 0; k < 32; ++k)
        hv[k] = h[(size_t)inv_t[rbase + k] * 64 + f];

    float w1 = 0.f, w2 = 0.f;
    #pragma unroll
    for (int k = 0; k < 32; ++k) {
        w1 = fmaf(cf1[rbase + k], hv[k], w1);
        w2 = fmaf(cf2[rbase + k], hv[k], w2);
    }
    __shared__ float ws[2][4][64];
    ws[0][wave][f] = w1;
    ws[1][wave][f] = w2;
    __syncthreads();
    if (wave == 0)
        T1[tile * 64 + f] = ws[0][0][f] + ws[0][1][f] + ws[0][2][f] + ws[0][3][f];
    else if (wave == 1)
        T2[tile * 64 + f] = ws[1][0][f] + ws[1][1][f] + ws[1][2][f] + ws[1][3][f];

    __threadfence();
    cg::this_grid().sync();

    // ----- S1: inclusive suffix of cf1*h over sorted rows -----
    {
        float a0 = 0.f, a1 = 0.f, a2 = 0.f, a3 = 0.f;
        int tt = tile + 1;
        for (; tt + 3 < 64; tt += 4) {
            a0 += T1[(tt + 0) * 64 + f];
            a1 += T1[(tt + 1) * 64 + f];
            a2 += T1[(tt + 2) * 64 + f];
            a3 += T1[(tt + 3) * 64 + f];
        }
        for (; tt < 64; ++tt) a0 += T1[tt * 64 + f];
        float acc = (a0 + a1) + (a2 + a3);
        for (int w = wave + 1; w < 4; ++w) acc += ws[0][w][f];
        #pragma unroll
        for (int k = 31; k >= 0; --k) {
            acc = fmaf(cf1[rbase + k], hv[k], acc);
            S1[(size_t)(rbase + k) * 64 + f] = acc;
        }
        if (tile == 63 && wave == 0) S1[(size_t)8192 * 64 + f] = 0.f;
    }
    // ----- S2: exclusive prefix of cf2*h over sorted rows -----
    {
        float a0 = 0.f, a1 = 0.f, a2 = 0.f, a3 = 0.f;
        int tt = 0;
        for (; tt + 3 < tile; tt += 4) {
            a0 += T2[(tt + 0) * 64 + f];
            a1 += T2[(tt + 1) * 64 + f];
            a2 += T2[(tt + 2) * 64 + f];
            a3 += T2[(tt + 3) * 64 + f];
        }
        for (; tt < tile; ++tt) a0 += T2[tt * 64 + f];
        float acc = (a0 + a1) + (a2 + a3);
        for (int w = 0; w < wave; ++w) acc += ws[1][w][f];
        #pragma unroll
        for (int k = 0; k < 32; ++k) {
            S2[(size_t)(rbase + k) * 64 + f] = acc;
            acc = fmaf(cf2[rbase + k], hv[k], acc);
        }
        if (tile == 63 && wave == 3) S2[(size_t)8192 * 64 + f] = acc;  // total
    }
}

// ---------------------------------------------------------------------------
// K5: out[i,f] = elu( e^{s_i-smax}*S1[pos_i][f] + e^{a(s_i-smax)}*S2[pos_i][f] )
// ---------------------------------------------------------------------------
__global__ __launch_bounds__(256) void k_out(
    const float* __restrict__ s, const float* __restrict__ smax_p,
    const int* __restrict__ pos,
    const float* __restrict__ S1, const float* __restrict__ S2,
    float* __restrict__ out)
{
    const int i = blockIdx.x * 4 + (__builtin_amdgcn_readfirstlane(threadIdx.x) >> 6);
    const int f = threadIdx.x & 63;
    const float d = s[i] - smax_p[0];
    const float e1 = __expf(d), e2 = __expf(ALPHA * d);
    const int p = pos[i];
    const float v = fmaf(e1, S1[(size_t)p * 64 + f], e2 * S2[(size_t)p * 64 + f]);
    out[(size_t)i * 64 + f] = v > 0.f ? v : expm1f(v);
}

// ---------------------------------------------------------------------------
extern "C" void kernel_launch(void* const* d_in, const int* in_sizes, int n_in,
                              void* d_out, int out_size, void* d_ws, size_t ws_size,
                              hipStream_t stream)
{
    // dict order: input, adj (unused by reference), intent_embeds, W, a
    const float* x  = (const float*)d_in[0];
    const float* ie = (const float*)d_in[2];
    const float* W  = (const float*)d_in[3];
    const float* a  = (const float*)d_in[4];
    float* out = (float*)d_out;

    float* p = (float*)d_ws;
    float* h        = p; p += (size_t)N_NODES * F_OUT;
    float* s        = p; p += N_NODES;
    float* t        = p; p += N_NODES;
    float* smax     = p; p += 16;
    float* se1      = p; p += N_NODES;
    float* se2      = p; p += N_NODES;
    float* t_sorted = p; p += N_NODES;
    float* cf1      = p; p += N_NODES;
    float* cf2      = p; p += N_NODES;
    float* T1       = p; p += 64 * 64;
    float* T2       = p; p += 64 * 64;
    float* S1       = p; p += (size_t)(N_NODES + 1) * F_OUT + 64;  // 8193 rows
    float* S2       = p; p += (size_t)(N_NODES + 1) * F_OUT + 64;
    int* pos        = (int*)p; p += N_NODES;
    int* inv_t      = (int*)p; p += N_NODES;
    int* q_sorted   = (int*)p; p += N_NODES;
    // 8-byte (in fact 16-byte) aligned: all preceding counts are even floats
    unsigned long long* su = (unsigned long long*)p; p += 2 * N_NODES;
    unsigned long long* tu = (unsigned long long*)p; p += 2 * N_NODES;
    // ~7 MB total, far under ws_size

    k_h_st <<<N_NODES, 64, 0, stream>>>(x, ie, W, a, h, s, t, su, tu);
    k_ranks<<<dim3(N_NODES / 32, 2), 256, 0, stream>>>(s, t, su, tu, smax,
                    pos, inv_t, t_sorted, q_sorted, se1, se2);
    k_mid  <<<1, 1024, 0, stream>>>(se1, se2, smax, t_sorted, q_sorted, cf1, cf2);
    {
        void* kargs[8] = { (void*)&h, (void*)&inv_t, (void*)&cf1, (void*)&cf2,
                           (void*)&T1, (void*)&T2, (void*)&S1, (void*)&S2 };
        (void)hipLaunchCooperativeKernel((const void*)k_scan, dim3(64), dim3(256),
                                         kargs, 0u, stream);
    }
    k_out  <<<N_NODES / 4, 256, 0, stream>>>(s, smax, pos, S1, S2, out);
}

// Round 2
// 355.484 us; speedup vs baseline: 1.1002x; 1.1002x over previous
//
#include <hip/hip_runtime.h>
#include <cstdint>
#include <cstddef>

#define N_NODES 8192
#define F_OUT   64
#define DINT    32
#define ALPHA   0.2f

__device__ __forceinline__ unsigned long long pack_vi(float v, int idx) {
    unsigned int b = __float_as_uint(v);
    b = (b & 0x80000000u) ? ~b : (b | 0x80000000u);   // sortable uint
    return ((unsigned long long)b << 32) | (unsigned int)idx;
}

// ---------------------------------------------------------------------------
// K1: h = x @ W, fused s,t projections + packed sortable keys su/tu.
// One wave per row.
// ---------------------------------------------------------------------------
__global__ __launch_bounds__(64) void k_h_st(
    const float* __restrict__ x, const float* __restrict__ ie,
    const float* __restrict__ W, const float* __restrict__ a,
    float* __restrict__ h, float* __restrict__ s, float* __restrict__ t,
    unsigned long long* __restrict__ su, unsigned long long* __restrict__ tu)
{
    const int i = blockIdx.x;
    const int f = threadIdx.x;              // 0..63
    const float* xr = x + (size_t)i * 64;

    float acc = 0.f;
    #pragma unroll 16
    for (int k = 0; k < 64; ++k)
        acc = fmaf(xr[k], W[k * 64 + f], acc);

    h[(size_t)i * 64 + f] = acc;

    float ps = acc * a[f];
    float pt = acc * a[64 + f];
    if (f < DINT) {
        float e = ie[(size_t)i * DINT + f];
        ps = fmaf(e, a[128 + f], ps);
        pt = fmaf(e, a[160 + f], pt);
    }
    #pragma unroll
    for (int m = 1; m < 64; m <<= 1) {
        ps += __shfl_xor(ps, m, 64);
        pt += __shfl_xor(pt, m, 64);
    }
    if (f == 0) {
        s[i] = ps; t[i] = pt;
        su[i] = pack_vi(ps, i);
        tu[i] = pack_vi(pt, i);
    }
}

// ---------------------------------------------------------------------------
// K2: ranks/counts. 8 keys per wave, 4 waves/block => 32 keys/block.
// Keys pre-packed (K1). LDS staging uses stride-256 element mapping:
// ds_write addr/4 = 2*tid (+512e) -> 4 accesses/bank = conflict-minimal,
// and the global loads are unit-stride coalesced.
//  which==0 (keys=s): rank_s -> scatter se1/se2; pos[i]=#{j: t_j < -s_i};
//                     wave u64-max of s gives smax for free.
//  which==1 (keys=t): inv_t[rank]=j, t_sorted[rank]=t_j, q[rank]=#{i: s_i<-t_j}.
// ---------------------------------------------------------------------------
__global__ __launch_bounds__(256) void k_ranks(
    const float* __restrict__ s, const float* __restrict__ t,
    const unsigned long long* __restrict__ su,
    const unsigned long long* __restrict__ tu,
    float* __restrict__ smax,
    int* __restrict__ pos, int* __restrict__ inv_t,
    float* __restrict__ t_sorted, int* __restrict__ q_sorted,
    float* __restrict__ se1, float* __restrict__ se2)
{
    __shared__ __align__(16) unsigned long long u_sh[2048];
    __shared__ __align__(16) float f_sh[2048];
    const int tid  = threadIdx.x;
    const int wave = tid >> 6;
    const int lane = tid & 63;
    const int which = blockIdx.y;
    const int key0 = blockIdx.x * 32 + wave * 8;

    const float* __restrict__ karr = (which == 0) ? s : t;
    const unsigned long long* __restrict__ kuarr = (which == 0) ? su : tu;
    const float* __restrict__ oarr = (which == 0) ? t : s;

    float kf[8], nk[8];
    unsigned long long ku[8];
    #pragma unroll
    for (int l = 0; l < 8; ++l) {
        kf[l] = karr[key0 + l];
        ku[l] = kuarr[key0 + l];
        nk[l] = -kf[l];
    }

    int c1[8] = {0,0,0,0,0,0,0,0}, c2[8] = {0,0,0,0,0,0,0,0};
    unsigned long long mx = 0ull;

    for (int c = 0; c < 4; ++c) {
        const int base = c * 2048;
        #pragma unroll
        for (int e = 0; e < 8; ++e) {
            u_sh[tid + e * 256] = kuarr[base + tid + e * 256];
            f_sh[tid + e * 256] = oarr[base + tid + e * 256];
        }
        __syncthreads();

        for (int k = lane * 4; k < 2048; k += 256) {
            const ulonglong2 p0 = *reinterpret_cast<const ulonglong2*>(&u_sh[k]);
            const ulonglong2 p1 = *reinterpret_cast<const ulonglong2*>(&u_sh[k + 2]);
            const float4 fv = *reinterpret_cast<const float4*>(&f_sh[k]);
            if (which == 0) {
                unsigned long long m01 = p0.x > p0.y ? p0.x : p0.y;
                unsigned long long m23 = p1.x > p1.y ? p1.x : p1.y;
                unsigned long long m03 = m01 > m23 ? m01 : m23;
                mx = mx > m03 ? mx : m03;
            }
            #pragma unroll
            for (int l = 0; l < 8; ++l) {
                c1[l] += (int)(p0.x < ku[l]) + (int)(p0.y < ku[l])
                       + (int)(p1.x < ku[l]) + (int)(p1.y < ku[l]);
                c2[l] += (int)(fv.x < nk[l]) + (int)(fv.y < nk[l])
                       + (int)(fv.z < nk[l]) + (int)(fv.w < nk[l]);
            }
        }
        __syncthreads();
    }

    int pk[8];
    #pragma unroll
    for (int l = 0; l < 8; ++l) pk[l] = c1[l] * 16384 + c2[l];
    #pragma unroll
    for (int m = 1; m < 64; m <<= 1) {
        #pragma unroll
        for (int l = 0; l < 8; ++l) pk[l] += __shfl_xor(pk[l], m, 64);
    }

    if (which == 0) {
        #pragma unroll
        for (int m = 1; m < 64; m <<= 1) {
            unsigned long long o = __shfl_xor(mx, m, 64);
            mx = mx > o ? mx : o;
        }
        if (lane == 0) {
            unsigned int b = (unsigned int)(mx >> 32);      // sortable of max s
            b = (b & 0x80000000u) ? (b ^ 0x80000000u) : ~b; // inverse map
            const float smax_f = __uint_as_float(b);
            if (key0 == 0) smax[0] = smax_f;
            #pragma unroll
            for (int l = 0; l < 8; ++l) {
                const int idx = key0 + l;
                const int r1 = pk[l] >> 14, r2 = pk[l] & 16383;
                pos[idx] = r2;
                const float d = kf[l] - smax_f;
                se1[r1] = __expf(d);
                se2[r1] = __expf(ALPHA * d);
            }
        }
    } else if (lane == 0) {
        #pragma unroll
        for (int l = 0; l < 8; ++l) {
            const int idx = key0 + l;
            const int r1 = pk[l] >> 14, r2 = pk[l] & 16383;
            inv_t[r1] = idx;
            t_sorted[r1] = kf[l];
            q_sorted[r1] = r2;
        }
    }
}

// ---------------------------------------------------------------------------
// K3 (single block, 1024 thr): fp64 scans via wave-shfl (2 barriers), then
// per-column coefficients. SufP1/PreP2 live only in LDS.
// ---------------------------------------------------------------------------
__global__ __launch_bounds__(1024) void k_mid(
    const float* __restrict__ se1, const float* __restrict__ se2,
    const float* __restrict__ smax_p,
    const float* __restrict__ t_sorted, const int* __restrict__ q_sorted,
    float* __restrict__ cf1, float* __restrict__ cf2)
{
    __shared__ float suf1[8200];
    __shared__ float pre2[8200];
    __shared__ double wred[2][16];
    const int tid = threadIdx.x, wave = tid >> 6, lane = tid & 63;
    const int base = tid * 8;

    double l1[8], l2[8], s1 = 0.0, s2 = 0.0;
    #pragma unroll
    for (int k = 0; k < 8; ++k) {
        l1[k] = (double)se1[base + k]; s1 += l1[k];
        l2[k] = (double)se2[base + k]; s2 += l2[k];
    }
    double i1 = s1, i2 = s2;                 // wave inclusive scan
    #pragma unroll
    for (int off = 1; off < 64; off <<= 1) {
        double v1 = __shfl_up(i1, off, 64);
        double v2 = __shfl_up(i2, off, 64);
        if (lane >= off) { i1 += v1; i2 += v2; }
    }
    if (lane == 63) { wred[0][wave] = i1; wred[1][wave] = i2; }
    __syncthreads();
    double off1 = 0, off2 = 0, tot1 = 0, tot2 = 0;
    #pragma unroll
    for (int w = 0; w < 16; ++w) {
        const double a = wred[0][w], b = wred[1][w];
        if (w < wave) { off1 += a; off2 += b; }
        tot1 += a; tot2 += b;
    }
    double run1 = off1 + (i1 - s1);          // exclusive prefix at `base`
    double run2 = off2 + (i2 - s2);
    #pragma unroll
    for (int k = 0; k < 8; ++k) {
        suf1[base + k] = (float)(tot1 - run1); run1 += l1[k];
        pre2[base + k] = (float)run2;          run2 += l2[k];
    }
    if (tid == 1023) { suf1[8192] = 0.f; pre2[8192] = (float)tot2; }
    __syncthreads();

    const float smax = smax_p[0];
    #pragma unroll
    for (int k = 0; k < 8; ++k) {
        const int r = tid + k * 1024;
        const float tj = t_sorted[r];
        const float zc = smax + tj;
        const float c = fmaxf(zc, ALPHA * zc);     // lrelu(smax+t_j) = col max
        const float E1 = __expf(zc - c);
        const float E2 = __expf(ALPHA * zc - c);
        const int qj = q_sorted[r];
        const float D = E1 * suf1[qj] + E2 * pre2[qj];
        const float invD = 1.f / D;
        cf1[r] = E1 * invD;
        cf2[r] = E2 * invD;
    }
}

// ---------------------------------------------------------------------------
// K4: per-tile (128 sorted rows) column sums of cf1*h and cf2*h (gathered).
// ---------------------------------------------------------------------------
__global__ __launch_bounds__(256) void k_tilesum(
    const float* __restrict__ h, const int* __restrict__ inv_t,
    const float* __restrict__ cf1, const float* __restrict__ cf2,
    float* __restrict__ T1, float* __restrict__ T2)
{
    const int tile = blockIdx.x;                 // 0..63
    const int wave = threadIdx.x >> 6, f = threadIdx.x & 63;
    const int r0 = tile * 128 + wave * 32;
    float a1 = 0.f, a2 = 0.f;
    for (int k = 0; k < 32; ++k) {
        const int r = r0 + k;
        const int j = inv_t[r];
        const float v = h[(size_t)j * 64 + f];
        a1 = fmaf(cf1[r], v, a1);
        a2 = fmaf(cf2[r], v, a2);
    }
    __shared__ float red[2][4][64];
    red[0][wave][f] = a1; red[1][wave][f] = a2;
    __syncthreads();
    if (wave == 0)
        T1[tile * 64 + f] = red[0][0][f] + red[0][1][f] + red[0][2][f] + red[0][3][f];
    else if (wave == 1)
        T2[tile * 64 + f] = red[1][0][f] + red[1][1][f] + red[1][2][f] + red[1][3][f];
}

// ---------------------------------------------------------------------------
// K5: fused final scans. One block per tile, 4 waves; each wave owns 32
// sorted rows, gathers its h rows ONCE into registers, computes per-wave
// partial sums for intra-tile offsets (LDS), adds cross-tile offsets from
// T1/T2 (4-acc unrolled), then walks both directions from cached hv[]:
//  S1[r] = inclusive suffix of cf1*h rows;  S1[8192]=0
//  S2[r] = exclusive prefix  of cf2*h rows; S2[8192]=total
// ---------------------------------------------------------------------------
__global__ __launch_bounds__(256) void k_scan2(
    const float* __restrict__ h, const int* __restrict__ inv_t,
    const float* __restrict__ cf1, const float* __restrict__ cf2,
    const float* __restrict__ T1, const float* __restrict__ T2,
    float* __restrict__ S1, float* __restrict__ S2)
{
    const int tile = blockIdx.x;                                   // 0..63
    const int wave = threadIdx.x >> 6;                             // 0..3
    const int f = threadIdx.x & 63;
    const int rbase = tile * 128 + wave * 32;

    float hv[32], c1v[32], c2v[32];
    #pragma unroll
    for (int k = 0; k < 32; ++k)
        hv[k] = h[(size_t)inv_t[rbase + k] * 64 + f];
    #pragma unroll
    for (int k = 0; k < 32; ++k) {
        c1v[k] = cf1[rbase + k];
        c2v[k] = cf2[rbase + k];
    }

    float w1 = 0.f, w2 = 0.f;
    #pragma unroll
    for (int k = 0; k < 32; ++k) {
        w1 = fmaf(c1v[k], hv[k], w1);
        w2 = fmaf(c2v[k], hv[k], w2);
    }
    __shared__ float ws[2][4][64];
    ws[0][wave][f] = w1;
    ws[1][wave][f] = w2;
    __syncthreads();

    // ----- S1: inclusive suffix of cf1*h over sorted rows -----
    {
        float a0 = 0.f, a1 = 0.f, a2 = 0.f, a3 = 0.f;
        int tt = tile + 1;
        for (; tt + 3 < 64; tt += 4) {
            a0 += T1[(tt + 0) * 64 + f];
            a1 += T1[(tt + 1) * 64 + f];
            a2 += T1[(tt + 2) * 64 + f];
            a3 += T1[(tt + 3) * 64 + f];
        }
        for (; tt < 64; ++tt) a0 += T1[tt * 64 + f];
        float acc = (a0 + a1) + (a2 + a3);
        for (int w = wave + 1; w < 4; ++w) acc += ws[0][w][f];
        #pragma unroll
        for (int k = 31; k >= 0; --k) {
            acc = fmaf(c1v[k], hv[k], acc);
            S1[(size_t)(rbase + k) * 64 + f] = acc;
        }
        if (tile == 63 && wave == 0) S1[(size_t)8192 * 64 + f] = 0.f;
    }
    // ----- S2: exclusive prefix of cf2*h over sorted rows -----
    {
        float a0 = 0.f, a1 = 0.f, a2 = 0.f, a3 = 0.f;
        int tt = 0;
        for (; tt + 3 < tile; tt += 4) {
            a0 += T2[(tt + 0) * 64 + f];
            a1 += T2[(tt + 1) * 64 + f];
            a2 += T2[(tt + 2) * 64 + f];
            a3 += T2[(tt + 3) * 64 + f];
        }
        for (; tt < tile; ++tt) a0 += T2[tt * 64 + f];
        float acc = (a0 + a1) + (a2 + a3);
        for (int w = 0; w < wave; ++w) acc += ws[1][w][f];
        #pragma unroll
        for (int k = 0; k < 32; ++k) {
            S2[(size_t)(rbase + k) * 64 + f] = acc;
            acc = fmaf(c2v[k], hv[k], acc);
        }
        if (tile == 63 && wave == 3) S2[(size_t)8192 * 64 + f] = acc;  // total
    }
}

// ---------------------------------------------------------------------------
// K6: out[i,f] = elu( e^{s_i-smax}*S1[pos_i][f] + e^{a(s_i-smax)}*S2[pos_i][f] )
// ---------------------------------------------------------------------------
__global__ __launch_bounds__(256) void k_out(
    const float* __restrict__ s, const float* __restrict__ smax_p,
    const int* __restrict__ pos,
    const float* __restrict__ S1, const float* __restrict__ S2,
    float* __restrict__ out)
{
    const int i = blockIdx.x * 4 + (threadIdx.x >> 6);
    const int f = threadIdx.x & 63;
    const float d = s[i] - smax_p[0];
    const float e1 = __expf(d), e2 = __expf(ALPHA * d);
    const int p = pos[i];
    const float v = fmaf(e1, S1[(size_t)p * 64 + f], e2 * S2[(size_t)p * 64 + f]);
    out[(size_t)i * 64 + f] = v > 0.f ? v : expm1f(v);
}

// ---------------------------------------------------------------------------
extern "C" void kernel_launch(void* const* d_in, const int* in_sizes, int n_in,
                              void* d_out, int out_size, void* d_ws, size_t ws_size,
                              hipStream_t stream)
{
    // dict order: input, adj (unused by reference), intent_embeds, W, a
    const float* x  = (const float*)d_in[0];
    const float* ie = (const float*)d_in[2];
    const float* W  = (const float*)d_in[3];
    const float* a  = (const float*)d_in[4];
    float* out = (float*)d_out;

    float* p = (float*)d_ws;
    float* h        = p; p += (size_t)N_NODES * F_OUT;
    float* s        = p; p += N_NODES;
    float* t        = p; p += N_NODES;
    float* smax     = p; p += 16;
    float* se1      = p; p += N_NODES;
    float* se2      = p; p += N_NODES;
    float* t_sorted = p; p += N_NODES;
    float* cf1      = p; p += N_NODES;
    float* cf2      = p; p += N_NODES;
    float* T1       = p; p += 64 * 64;
    float* T2       = p; p += 64 * 64;
    float* S1       = p; p += (size_t)(N_NODES + 1) * F_OUT + 64;  // 8193 rows
    float* S2       = p; p += (size_t)(N_NODES + 1) * F_OUT + 64;
    int* pos        = (int*)p; p += N_NODES;
    int* inv_t      = (int*)p; p += N_NODES;
    int* q_sorted   = (int*)p; p += N_NODES;
    // all preceding counts are even floats -> su/tu are 8B aligned
    unsigned long long* su = (unsigned long long*)p; p += 2 * N_NODES;
    unsigned long long* tu = (unsigned long long*)p; p += 2 * N_NODES;
    // ~7.3 MB total, far under ws_size

    k_h_st   <<<N_NODES, 64, 0, stream>>>(x, ie, W, a, h, s, t, su, tu);
    k_ranks  <<<dim3(N_NODES / 32, 2), 256, 0, stream>>>(s, t, su, tu, smax,
                     pos, inv_t, t_sorted, q_sorted, se1, se2);
    k_mid    <<<1, 1024, 0, stream>>>(se1, se2, smax, t_sorted, q_sorted,
                     cf1, cf2);
    k_tilesum<<<64, 256, 0, stream>>>(h, inv_t, cf1, cf2, T1, T2);
    k_scan2  <<<64, 256, 0, stream>>>(h, inv_t, cf1, cf2, T1, T2, S1, S2);
    k_out    <<<N_NODES / 4, 256, 0, stream>>>(s, smax, pos, S1, S2, out);
}